// Round 12
// baseline (212.275 us; speedup 1.0000x reference)
//
#include <hip/hip_runtime.h>
#include <stdint.h>

#define B_ 2
#define S_ 1024
#define D_ 768
#define H_ 12
#define DH 64
#define G_ 4
#define DG 192
#define T_ 2047
#define SCALEF 0.125f

typedef unsigned short u16;
typedef unsigned int u32;
typedef __attribute__((ext_vector_type(8))) short short8;
typedef __attribute__((ext_vector_type(4))) float floatx4;

__device__ __forceinline__ float uas(u32 x){ union { u32 i; float f; } v; v.i = x; return v.f; }
__device__ __forceinline__ float bf2f(u16 u){ return uas(((u32)u) << 16); }
__device__ __forceinline__ u16 f2bf(float f){
    union { float f; u32 i; } v; v.f = f;
    u32 x = v.i;
    u32 r = (x + 0x7fffu + ((x >> 16) & 1u)) >> 16;  // RNE
    return (u16)r;
}
__device__ __forceinline__ short8 cvt8(float4 x, float4 y){
    union { u16 h[8]; short8 v; } u;
    u.h[0]=f2bf(x.x); u.h[1]=f2bf(x.y); u.h[2]=f2bf(x.z); u.h[3]=f2bf(x.w);
    u.h[4]=f2bf(y.x); u.h[5]=f2bf(y.y); u.h[6]=f2bf(y.z); u.h[7]=f2bf(y.w);
    return u.v;
}

// ---------------- Kernel PRE: merged proj (0..767) + rhead (768..1535) ----------------
// Both single-barrier: W strip staged to LDS once; A fragments direct global->VGPR.
__global__ __launch_bounds__(256) void pre_kernel(
    const float* __restrict__ query,
    const float* __restrict__ Wq, const float* __restrict__ Wk, const float* __restrict__ Wv,
    const float* __restrict__ bk, const float* __restrict__ bv,
    u16* __restrict__ qq, u16* __restrict__ ko, u16* __restrict__ vt,
    const float* __restrict__ pe, const float* __restrict__ rk,
    u16* __restrict__ R)
{
    __shared__ __align__(16) char sm[49664];
    int tid  = threadIdx.x;
    int wave = tid >> 6, lane = tid & 63;
    int qm   = lane & 15;
    int quad = lane >> 4;
    int id = blockIdx.x;
    int sn = tid & 31, sk = tid >> 5;       // staging: col n, k phase

    if (id < 768) {
        // ========== proj: 64 rows x (group g, 32 cols) ; K=192, ONE barrier ==========
        typedef u16 (*W3T)[32][200];        // [md][n][k] pad->2-way-free
        W3T Ws = (W3T)sm;
        int m0 = (id & 31) * 64;
        int gy = id >> 5;                   // 0..23
        int g  = gy / 6;
        int n0 = (gy % 6) * 32;
        const float* Wm[3] = { Wq, Wk, Wv };

        // A loads (fp32, issued first to overlap staging)
        int row = m0 + wave*16 + qm;
        const float* Ab = query + (size_t)row*D_ + g*DG;
        float4 fx[6], fy[6];
        #pragma unroll
        for (int kc = 0; kc < 6; kc++) {
            fx[kc] = *(const float4*)(Ab + kc*32 + quad*8);
            fy[kc] = *(const float4*)(Ab + kc*32 + quad*8 + 4);
        }
        // stage W strips (once)
        #pragma unroll
        for (int md = 0; md < 3; md++) {
            const float* W = Wm[md] + (size_t)g*DG*DG + n0 + sn;
            #pragma unroll
            for (int k = 0; k < 24; k++)
                Ws[md][sn][sk + k*8] = f2bf(W[(size_t)(sk + k*8)*DG]);
        }
        __syncthreads();

        short8 af[6];
        #pragma unroll
        for (int kc = 0; kc < 6; kc++) af[kc] = cvt8(fx[kc], fy[kc]);

        floatx4 acc[3][2];
        #pragma unroll
        for (int md = 0; md < 3; md++) { acc[md][0] = (floatx4){0,0,0,0}; acc[md][1] = (floatx4){0,0,0,0}; }
        #pragma unroll
        for (int kc = 0; kc < 6; kc++) {
            short8 a = af[kc];
            #pragma unroll
            for (int md = 0; md < 3; md++) {
                #pragma unroll
                for (int bt = 0; bt < 2; bt++) {
                    short8 b = *(const short8*)&Ws[md][bt*16 + qm][kc*32 + quad*8];
                    acc[md][bt] = __builtin_amdgcn_mfma_f32_16x16x32_bf16(a, b, acc[md][bt], 0,0,0);
                }
            }
        }

        int rowbase = m0 + wave*16 + quad*4;
        int b  = rowbase >> 10;
        int s0 = rowbase & 1023;
        #pragma unroll
        for (int bt = 0; bt < 2; bt++) {
            int c = g*DG + n0 + bt*16 + qm;
            int n = c >> 6, d = c & 63;
            int bn = b*H_ + n;
            float bkv = bk[c], bvv = bv[c];
            #pragma unroll
            for (int gg = 0; gg < 4; gg++) {
                size_t o = ((size_t)bn*S_ + s0 + gg)*DH + d;
                qq[o] = f2bf(acc[0][bt][gg]*SCALEF);
                ko[o] = f2bf(acc[1][bt][gg] + bkv);
            }
            union { u16 h[4]; uint2 v; } vv;
            #pragma unroll
            for (int gg = 0; gg < 4; gg++) vv.h[gg] = f2bf(acc[2][bt][gg] + bvv);
            *(uint2*)(vt + ((size_t)bn*DH + d)*S_ + s0) = vv.v;
        }
    } else {
        // ========== rhead: pe[2047,768] @ rk -> R ; 64 rows x 32 cols, K=768, ONE barrier ==========
        typedef u16 (*WsT)[776];
        WsT Ws = (WsT)sm;                   // [32][776]
        int id2 = id - 768;
        int m0 = (id2 & 31) * 64;
        int n0 = (id2 >> 5) * 32;

        int row = m0 + wave*16 + qm;
        int rowc = (row <= 2046) ? row : 2046;
        const float* Ab = pe + (size_t)rowc*D_;

        // ring prefetch depth 4 (fp32)
        float4 fr[4][2];
        #pragma unroll
        for (int t = 0; t < 4; t++) {
            fr[t][0] = *(const float4*)(Ab + t*32 + quad*8);
            fr[t][1] = *(const float4*)(Ab + t*32 + quad*8 + 4);
        }
        // stage rk strip (once)
        {
            const float* W = rk + n0 + sn;
            #pragma unroll
            for (int k = 0; k < 96; k++)
                Ws[sn][sk + k*8] = f2bf(W[(size_t)(sk + k*8)*D_]);
        }
        __syncthreads();

        floatx4 acc[2];
        acc[0] = (floatx4){0,0,0,0};
        acc[1] = (floatx4){0,0,0,0};
        #pragma unroll
        for (int kc = 0; kc < 24; kc++) {
            float4 x = fr[kc & 3][0], y = fr[kc & 3][1];
            if (kc < 20) {
                fr[kc & 3][0] = *(const float4*)(Ab + (kc+4)*32 + quad*8);
                fr[kc & 3][1] = *(const float4*)(Ab + (kc+4)*32 + quad*8 + 4);
            }
            short8 a = cvt8(x, y);
            #pragma unroll
            for (int bt = 0; bt < 2; bt++) {
                short8 b = *(const short8*)&Ws[bt*16 + qm][kc*32 + quad*8];
                acc[bt] = __builtin_amdgcn_mfma_f32_16x16x32_bf16(a, b, acc[bt], 0,0,0);
            }
        }

        #pragma unroll
        for (int bt = 0; bt < 2; bt++) {
            int c = n0 + bt*16 + qm;
            #pragma unroll
            for (int g = 0; g < 4; g++) {
                int r2 = m0 + wave*16 + quad*4 + g;
                if (r2 < T_)
                    R[((size_t)(c >> 6)*T_ + r2)*DH + (c & 63)] = f2bf(acc[bt][g]);
            }
        }
    }
}

// ---------------- out GEMM: h = av(bf16) @ Wo + bo + query ; single barrier ----------------
__global__ __launch_bounds__(256) void gemm_out_kernel(
    const u16* __restrict__ A, const float* __restrict__ W,
    const float* __restrict__ bias, const float* __restrict__ resid,
    float* __restrict__ outf)
{
    __shared__ __align__(16) u16 Ws[32][776];
    int tid  = threadIdx.x;
    int wave = tid >> 6, lane = tid & 63;
    int qm   = lane & 15;
    int quad = lane >> 4;
    int id = blockIdx.x;
    int m0 = (id & 31) * 64;
    int n0 = (id >> 5) * 32;
    int sn = tid & 31, sk = tid >> 5;

    int row = m0 + wave*16 + qm;
    const u16* Ab = A + (size_t)row*D_;

    // ring prefetch depth 8 (bf16 direct)
    short8 ar[8];
    #pragma unroll
    for (int t = 0; t < 8; t++) ar[t] = *(const short8*)(Ab + t*32 + quad*8);
    // stage Wo strip (once)
    {
        const float* Wb = W + n0 + sn;
        #pragma unroll
        for (int k = 0; k < 96; k++)
            Ws[sn][sk + k*8] = f2bf(Wb[(size_t)(sk + k*8)*D_]);
    }
    __syncthreads();

    floatx4 acc[2];
    acc[0] = (floatx4){0,0,0,0};
    acc[1] = (floatx4){0,0,0,0};
    #pragma unroll
    for (int kc = 0; kc < 24; kc++) {
        short8 a = ar[kc & 7];
        if (kc < 16) ar[kc & 7] = *(const short8*)(Ab + (kc+8)*32 + quad*8);
        #pragma unroll
        for (int bt = 0; bt < 2; bt++) {
            short8 b = *(const short8*)&Ws[bt*16 + qm][kc*32 + quad*8];
            acc[bt] = __builtin_amdgcn_mfma_f32_16x16x32_bf16(a, b, acc[bt], 0,0,0);
        }
    }

    #pragma unroll
    for (int bt = 0; bt < 2; bt++) {
        int c = n0 + bt*16 + qm;
        #pragma unroll
        for (int g = 0; g < 4; g++) {
            int r2 = m0 + wave*16 + quad*4 + g;
            outf[(size_t)r2*D_ + c] = acc[bt][g] + bias[c] + resid[(size_t)r2*D_ + c];
        }
    }
}

// ---------------- Kernel C: MFMA fused rel-attention v4 (unchanged, verified) ----------------
__global__ __launch_bounds__(256, 2) void attn_kernel(
    const u16* __restrict__ qq,
    const u16* __restrict__ kk, const u16* __restrict__ vt,
    const u16* __restrict__ R,
    const float* __restrict__ rwb, const float* __restrict__ rrb,
    u16* __restrict__ av)
{
    __shared__ char smem[64*1024];
    u16* SC  = (u16*)smem;
    u16* PSC = (u16*)(smem + 32768);
    int tid  = threadIdx.x;
    int wave = tid >> 6, lane = tid & 63;
    int qm   = lane & 15;
    int quad = lane >> 4;
    int k8   = quad * 8;
    int blkid = blockIdx.x;
    int xcd = blkid & 7;
    int sl  = blkid >> 3;
    int it  = sl & 63;
    int seg = sl >> 6;
    int bn  = xcd + 8*seg;
    int b = bn / H_, n = bn % H_;
    int i0 = it * 16;
    size_t hbase = (size_t)bn * S_ * DH;

    short8 qcf[2], qpf[2];
    #pragma unroll
    for (int s = 0; s < 2; s++) {
        const u16* qptr = qq + hbase + (size_t)(i0 + qm)*DH + s*32 + k8;
        const float* rwp = rwb + n*DH + s*32 + k8;
        const float* rrp = rrb + n*DH + s*32 + k8;
        #pragma unroll
        for (int j = 0; j < 8; j++) {
            float qv = bf2f(qptr[j]);
            qcf[s][j] = (short)f2bf(qv + rwp[j]*SCALEF);
            qpf[s][j] = (short)f2bf(qv + rrp[j]*SCALEF);
        }
    }

    {
        const u16* kbb = kk + hbase + (size_t)qm*DH + k8;
        short8 rb[8][2];
        #pragma unroll
        for (int t = 0; t < 8; t++) {
            const u16* kp = kbb + (size_t)((wave*16 + t)*16)*DH;
            rb[t][0] = *(const short8*)(kp);
            rb[t][1] = *(const short8*)(kp + 32);
        }
        #pragma unroll
        for (int t = 0; t < 16; t++) {
            short8 b0 = rb[t & 7][0], b1 = rb[t & 7][1];
            if (t < 8) {
                const u16* kp = kbb + (size_t)((wave*16 + t + 8)*16)*DH;
                rb[t & 7][0] = *(const short8*)(kp);
                rb[t & 7][1] = *(const short8*)(kp + 32);
            }
            floatx4 acc = {0.f,0.f,0.f,0.f};
            acc = __builtin_amdgcn_mfma_f32_16x16x32_bf16(qcf[0], b0, acc, 0,0,0);
            acc = __builtin_amdgcn_mfma_f32_16x16x32_bf16(qcf[1], b1, acc, 0,0,0);
            int j0 = (wave*16 + t) * 16;
            #pragma unroll
            for (int g = 0; g < 4; g++)
                SC[(quad*4 + g)*1024 + j0 + qm] = f2bf(acc[g]);
        }
    }

    int ubase = 1008 - i0;
    {
        const u16* rbb = R + (size_t)n*T_*DH + k8;
        short8 rb[8][2];
        int us[8];
        #pragma unroll
        for (int t = 0; t < 8; t++) {
            int m = t*4 + wave;
            int uu = ubase + m*16 + qm;
            int ur = (uu <= 2046) ? uu : 2046;
            us[t] = uu;
            const u16* rp = rbb + (size_t)ur*DH;
            rb[t][0] = *(const short8*)(rp);
            rb[t][1] = *(const short8*)(rp + 32);
        }
        #pragma unroll
        for (int t = 0; t < 16; t++) {
            short8 b0 = rb[t & 7][0], b1 = rb[t & 7][1];
            int uu = us[t & 7];
            if (t < 8) {
                int m2 = (t + 8)*4 + wave;
                int uu2 = ubase + m2*16 + qm;
                int ur2 = (uu2 <= 2046) ? uu2 : 2046;
                us[t & 7] = uu2;
                const u16* rp = rbb + (size_t)ur2*DH;
                rb[t & 7][0] = *(const short8*)(rp);
                rb[t & 7][1] = *(const short8*)(rp + 32);
            }
            floatx4 acc = {0.f,0.f,0.f,0.f};
            acc = __builtin_amdgcn_mfma_f32_16x16x32_bf16(qpf[0], b0, acc, 0,0,0);
            acc = __builtin_amdgcn_mfma_f32_16x16x32_bf16(qpf[1], b1, acc, 0,0,0);
            #pragma unroll
            for (int g = 0; g < 4; g++) {
                int row = quad*4 + g;
                int j = uu + i0 + row - 1024;
                if (j >= 0 && j < S_ && uu <= 2046)
                    PSC[row*1024 + j] = f2bf(acc[g]);
            }
        }
    }
    if (wave == 0) {
        int uu = ubase + 64*16 + qm;
        int ur = (uu <= 2046) ? uu : 2046;
        const u16* rp = R + ((size_t)n*T_ + ur)*DH + k8;
        short8 b0 = *(const short8*)(rp);
        short8 b1 = *(const short8*)(rp + 32);
        floatx4 acc = {0.f,0.f,0.f,0.f};
        acc = __builtin_amdgcn_mfma_f32_16x16x32_bf16(qpf[0], b0, acc, 0,0,0);
        acc = __builtin_amdgcn_mfma_f32_16x16x32_bf16(qpf[1], b1, acc, 0,0,0);
        #pragma unroll
        for (int g = 0; g < 4; g++) {
            int row = quad*4 + g;
            int j = uu + i0 + row - 1024;
            if (j >= 0 && j < S_ && uu <= 2046)
                PSC[row*1024 + j] = f2bf(acc[g]);
        }
    }
    if (i0 == 0 && tid == 0) {
        float sdot = 0.f;
        const u16* r0p = R + (size_t)n*T_*DH;
        const u16* q1p = qq + hbase + DH;
        for (int d = 0; d < DH; d++)
            sdot += (bf2f(q1p[d]) + rrb[n*DH + d]*SCALEF) * bf2f(r0p[d]);
        PSC[1023] = f2bf(sdot);
    }
    __syncthreads();

    for (int rr = 0; rr < 4; rr++) {
        int r = wave*4 + rr;
        short8 c0 = *(const short8*)(SC  + r*1024 + lane*16);
        short8 c1 = *(const short8*)(SC  + r*1024 + lane*16 + 8);
        short8 p0 = *(const short8*)(PSC + r*1024 + lane*16);
        short8 p1 = *(const short8*)(PSC + r*1024 + lane*16 + 8);
        float p[16];
        float mx = -1e30f;
        #pragma unroll
        for (int q = 0; q < 8; q++) {
            p[q]   = bf2f((u16)c0[q]) + bf2f((u16)p0[q]);
            p[q+8] = bf2f((u16)c1[q]) + bf2f((u16)p1[q]);
        }
        #pragma unroll
        for (int q = 0; q < 16; q++) mx = fmaxf(mx, p[q]);
        #pragma unroll
        for (int off = 32; off; off >>= 1) mx = fmaxf(mx, __shfl_xor(mx, off));
        float ssum = 0.f;
        #pragma unroll
        for (int q = 0; q < 16; q++) { p[q] = __expf(p[q] - mx); ssum += p[q]; }
        #pragma unroll
        for (int off = 32; off; off >>= 1) ssum += __shfl_xor(ssum, off);
        float inv = 1.0f / ssum;
        int swz = r & 7;
        union { u16 h[8]; short8 v; } w0, w1;
        #pragma unroll
        for (int q = 0; q < 8; q++) {
            w0.h[q] = f2bf(p[q]*inv);
            w1.h[q] = f2bf(p[q+8]*inv);
        }
        *(short8*)(SC + r*1024 + (((2*lane)   ^ swz) << 3)) = w0.v;
        *(short8*)(SC + r*1024 + (((2*lane+1) ^ swz) << 3)) = w1.v;
    }

    int d0 = wave*16;
    const u16* vbase = vt + ((size_t)bn*DH + d0 + qm)*S_;
    short8 vb[8];
    #pragma unroll
    for (int t = 0; t < 8; t++) vb[t] = *(const short8*)(vbase + t*32 + k8);
    __syncthreads();

    floatx4 o[4];
    #pragma unroll
    for (int t = 0; t < 4; t++) o[t] = (floatx4){0.f,0.f,0.f,0.f};
    int aswz = qm & 7;
    #pragma unroll
    for (int kt = 0; kt < 32; kt++) {
        short8 bfr = vb[kt & 7];
        if (kt < 24) vb[kt & 7] = *(const short8*)(vbase + (kt + 8)*32 + k8);
        int chunk = (kt*4 + quad) ^ aswz;
        short8 a = *(const short8*)(SC + qm*1024 + (chunk << 3));
        o[kt & 3] = __builtin_amdgcn_mfma_f32_16x16x32_bf16(a, bfr, o[kt & 3], 0,0,0);
    }
    floatx4 os = (o[0] + o[1]) + (o[2] + o[3]);
    #pragma unroll
    for (int g = 0; g < 4; g++) {
        int row = quad*4 + g;
        av[((size_t)(b*S_) + i0 + row)*D_ + n*DH + d0 + qm] = f2bf(os[g]);
    }
}

// ---------------- Kernel E: in-place LayerNorm (float4 I/O) ----------------
__global__ __launch_bounds__(256) void ln_kernel(
    const float* __restrict__ gamma, const float* __restrict__ beta,
    float* out)
{
    __shared__ float hb[8][D_];
    int tid = threadIdx.x;
    int rowg0 = blockIdx.x * 8;
    #pragma unroll
    for (int p = 0; p < 6; p++) {
        int id = p*256 + tid;
        int r = id / 192, e4 = id % 192;
        *(float4*)&hb[r][e4*4] = *(const float4*)&out[(size_t)(rowg0 + r)*D_ + e4*4];
    }
    __syncthreads();
    int wave = tid >> 6, lane = tid & 63;
    for (int rr = 0; rr < 2; rr++) {
        int r = wave*2 + rr;
        float s = 0.f;
        #pragma unroll
        for (int kq = 0; kq < 12; kq++) s += hb[r][lane + kq*64];
        #pragma unroll
        for (int off = 32; off; off >>= 1) s += __shfl_xor(s, off);
        float mu = s * (1.0f/768.0f);
        float vsum = 0.f;
        #pragma unroll
        for (int kq = 0; kq < 12; kq++) { float d = hb[r][lane + kq*64] - mu; vsum += d*d; }
        #pragma unroll
        for (int off = 32; off; off >>= 1) vsum += __shfl_xor(vsum, off);
        float rstd = rsqrtf(vsum * (1.0f/768.0f) + 1e-9f);
        #pragma unroll
        for (int kq = 0; kq < 3; kq++) {
            int c4 = lane + kq*64;
            float4 g4 = *(const float4*)&gamma[c4*4];
            float4 b4 = *(const float4*)&beta[c4*4];
            float4 h4 = *(const float4*)&hb[r][c4*4];
            float4 o4;
            o4.x = (h4.x - mu)*rstd*g4.x + b4.x;
            o4.y = (h4.y - mu)*rstd*g4.y + b4.y;
            o4.z = (h4.z - mu)*rstd*g4.z + b4.z;
            o4.w = (h4.w - mu)*rstd*g4.w + b4.w;
            *(float4*)&out[(size_t)(rowg0 + r)*D_ + c4*4] = o4;
        }
    }
}

extern "C" void kernel_launch(void* const* d_in, const int* in_sizes, int n_in,
                              void* d_out, int out_size, void* d_ws, size_t ws_size,
                              hipStream_t stream) {
    const float* query = (const float*)d_in[0];
    const float* pe    = (const float*)d_in[1];
    const float* Wq    = (const float*)d_in[2];
    const float* Wk    = (const float*)d_in[3];
    const float* bk    = (const float*)d_in[4];
    const float* Wv    = (const float*)d_in[5];
    const float* bv    = (const float*)d_in[6];
    const float* rk    = (const float*)d_in[7];
    const float* rwb   = (const float*)d_in[8];
    const float* rrb   = (const float*)d_in[9];
    const float* Wo    = (const float*)d_in[10];
    const float* bo    = (const float*)d_in[11];
    const float* gamma = (const float*)d_in[12];
    const float* beta  = (const float*)d_in[13];
    float* out = (float*)d_out;

    u16* ws = (u16*)d_ws;
    const size_t SEG = (size_t)B_*H_*S_*DH;       // 1,572,864 elems (3 MB bf16)
    u16* qq = ws;             // [bn][s][d]
    u16* kk = qq + SEG;       // [bn][s][d]
    u16* vt = kk + SEG;       // [bn][d][s]  (transposed V)
    u16* R  = vt + SEG;       // [n][2047][d]
    u16* av = R + SEG;        // [b*S+s][n*64+d] bf16 attn_vec

    pre_kernel<<<1536, 256, 0, stream>>>(query, Wq, Wk, Wv, bk, bv, qq, kk, vt, pe, rk, R);
    attn_kernel<<<1536, 256, 0, stream>>>(qq, kk, vt, R, rwb, rrb, av);
    gemm_out_kernel<<<768, 256, 0, stream>>>(av, Wo, bo, query, out);
    ln_kernel<<<256, 256, 0, stream>>>(gamma, beta, out);
}

// Round 13
// 177.725 us; speedup vs baseline: 1.1944x; 1.1944x over previous
//
#include <hip/hip_runtime.h>
#include <stdint.h>

#define B_ 2
#define S_ 1024
#define D_ 768
#define H_ 12
#define DH 64
#define G_ 4
#define DG 192
#define T_ 2047
#define SCALEF 0.125f

typedef unsigned short u16;
typedef unsigned int u32;
typedef __attribute__((ext_vector_type(8))) short short8;
typedef __attribute__((ext_vector_type(4))) float floatx4;

__device__ __forceinline__ float uas(u32 x){ union { u32 i; float f; } v; v.i = x; return v.f; }
__device__ __forceinline__ float bf2f(u16 u){ return uas(((u32)u) << 16); }
__device__ __forceinline__ u16 f2bf(float f){
    union { float f; u32 i; } v; v.f = f;
    u32 x = v.i;
    u32 r = (x + 0x7fffu + ((x >> 16) & 1u)) >> 16;  // RNE
    return (u16)r;
}
__device__ __forceinline__ short8 cvt8(float4 x, float4 y){
    union { u16 h[8]; short8 v; } u;
    u.h[0]=f2bf(x.x); u.h[1]=f2bf(x.y); u.h[2]=f2bf(x.z); u.h[3]=f2bf(x.w);
    u.h[4]=f2bf(y.x); u.h[5]=f2bf(y.y); u.h[6]=f2bf(y.z); u.h[7]=f2bf(y.w);
    return u.v;
}

// Fragment-plane layouts (all u16 units):
//  kf[bn][jt(64)]  : tile = 1024 u16 = {plane p(2)}[512] ; entry (p, lane, j) = K[jt*16+(lane&15)][p*32+(lane>>4)*8+j]
//  Rf[n][ut(128)]  : same shape; entry = Rhead[ut*16+(lane&15)][p*32+(lane>>4)*8+j]   (u=2047 slots unwritten, values discarded)
//  vf[bn][kt(32)]  : 4 dslices x 512 ; entry (ds, lane, j) = V[kt*32+(lane>>4)*8+j][ds*16+(lane&15)]

// ---------------- Kernel PRE: merged proj (0..767) + rhead (768..1535) ----------------
__global__ __launch_bounds__(256) void pre_kernel(
    const float* __restrict__ query,
    const float* __restrict__ Wq, const float* __restrict__ Wk, const float* __restrict__ Wv,
    const float* __restrict__ bk, const float* __restrict__ bv,
    u16* __restrict__ qq, u16* __restrict__ kf, u16* __restrict__ vf,
    const float* __restrict__ pe, const float* __restrict__ rk,
    u16* __restrict__ Rf)
{
    __shared__ __align__(16) char sm[49664];
    int tid  = threadIdx.x;
    int wave = tid >> 6, lane = tid & 63;
    int qm   = lane & 15;
    int quad = lane >> 4;
    int id = blockIdx.x;
    int sn = tid & 31, sk = tid >> 5;

    if (id < 768) {
        // ========== proj: 64 rows x (group g, 32 cols); K=192, ONE barrier ==========
        typedef u16 (*W3T)[32][200];
        W3T Ws = (W3T)sm;
        int m0 = (id & 31) * 64;
        int gy = id >> 5;
        int g  = gy / 6;
        int n0 = (gy % 6) * 32;
        const float* Wm[3] = { Wq, Wk, Wv };

        int row = m0 + wave*16 + qm;
        const float* Ab = query + (size_t)row*D_ + g*DG;
        float4 fx[6], fy[6];
        #pragma unroll
        for (int kc = 0; kc < 6; kc++) {
            fx[kc] = *(const float4*)(Ab + kc*32 + quad*8);
            fy[kc] = *(const float4*)(Ab + kc*32 + quad*8 + 4);
        }
        #pragma unroll
        for (int md = 0; md < 3; md++) {
            const float* W = Wm[md] + (size_t)g*DG*DG + n0 + sn;
            #pragma unroll
            for (int k = 0; k < 24; k++)
                Ws[md][sn][sk + k*8] = f2bf(W[(size_t)(sk + k*8)*DG]);
        }
        __syncthreads();

        short8 af[6];
        #pragma unroll
        for (int kc = 0; kc < 6; kc++) af[kc] = cvt8(fx[kc], fy[kc]);

        floatx4 acc[3][2];
        #pragma unroll
        for (int md = 0; md < 3; md++) { acc[md][0] = (floatx4){0,0,0,0}; acc[md][1] = (floatx4){0,0,0,0}; }
        #pragma unroll
        for (int kc = 0; kc < 6; kc++) {
            short8 a = af[kc];
            #pragma unroll
            for (int md = 0; md < 3; md++) {
                #pragma unroll
                for (int bt = 0; bt < 2; bt++) {
                    short8 b = *(const short8*)&Ws[md][bt*16 + qm][kc*32 + quad*8];
                    acc[md][bt] = __builtin_amdgcn_mfma_f32_16x16x32_bf16(a, b, acc[md][bt], 0,0,0);
                }
            }
        }

        int rowbase = m0 + wave*16 + quad*4;
        int b  = rowbase >> 10;
        int s0 = rowbase & 1023;
        #pragma unroll
        for (int bt = 0; bt < 2; bt++) {
            int c = g*DG + n0 + bt*16 + qm;
            int n = c >> 6, d = c & 63;
            int bn = b*H_ + n;
            int p  = d >> 5, dd = d & 31;
            int qv = (dd >> 3) * 16, jj = dd & 7;
            int ds = d >> 4, qmv = d & 15;
            float bkv = bk[c], bvv = bv[c];
            #pragma unroll
            for (int gg = 0; gg < 4; gg++) {
                int s = s0 + gg;
                qq[((size_t)bn*S_ + s)*DH + d] = f2bf(acc[0][bt][gg]*SCALEF);
                // K fragment plane
                kf[((size_t)bn*64 + (s>>4))*1024 + p*512 + (qv + (s&15))*8 + jj]
                    = f2bf(acc[1][bt][gg] + bkv);
                // V fragment plane
                vf[(((size_t)bn*32 + (s>>5))*4 + ds)*512 + (((s>>3)&3)*16 + qmv)*8 + (s&7)]
                    = f2bf(acc[2][bt][gg] + bvv);
            }
        }
    } else {
        // ========== rhead: pe[2047,768] @ rk -> Rf ; 64 rows x 32 cols, K=768, ONE barrier ==========
        typedef u16 (*WsT)[776];
        WsT Ws = (WsT)sm;
        int id2 = id - 768;
        int m0 = (id2 & 31) * 64;
        int n0 = (id2 >> 5) * 32;

        int row = m0 + wave*16 + qm;
        int rowc = (row <= 2046) ? row : 2046;
        const float* Ab = pe + (size_t)rowc*D_;

        float4 fr[4][2];
        #pragma unroll
        for (int t = 0; t < 4; t++) {
            fr[t][0] = *(const float4*)(Ab + t*32 + quad*8);
            fr[t][1] = *(const float4*)(Ab + t*32 + quad*8 + 4);
        }
        {
            const float* W = rk + n0 + sn;
            #pragma unroll
            for (int k = 0; k < 96; k++)
                Ws[sn][sk + k*8] = f2bf(W[(size_t)(sk + k*8)*D_]);
        }
        __syncthreads();

        floatx4 acc[2];
        acc[0] = (floatx4){0,0,0,0};
        acc[1] = (floatx4){0,0,0,0};
        #pragma unroll
        for (int kc = 0; kc < 24; kc++) {
            float4 x = fr[kc & 3][0], y = fr[kc & 3][1];
            if (kc < 20) {
                fr[kc & 3][0] = *(const float4*)(Ab + (kc+4)*32 + quad*8);
                fr[kc & 3][1] = *(const float4*)(Ab + (kc+4)*32 + quad*8 + 4);
            }
            short8 a = cvt8(x, y);
            #pragma unroll
            for (int bt = 0; bt < 2; bt++) {
                short8 b = *(const short8*)&Ws[bt*16 + qm][kc*32 + quad*8];
                acc[bt] = __builtin_amdgcn_mfma_f32_16x16x32_bf16(a, b, acc[bt], 0,0,0);
            }
        }

        #pragma unroll
        for (int bt = 0; bt < 2; bt++) {
            int c = n0 + bt*16 + qm;
            int n = c >> 6, d = c & 63;
            int p = d >> 5, dd = d & 31;
            int qv = (dd >> 3) * 16, jj = dd & 7;
            #pragma unroll
            for (int g = 0; g < 4; g++) {
                int t = m0 + wave*16 + quad*4 + g;
                if (t < T_)
                    Rf[((size_t)n*128 + (t>>4))*1024 + p*512 + (qv + (t&15))*8 + jj]
                        = f2bf(acc[bt][g]);
            }
        }
    }
}

// ---------------- out GEMM: h = av(bf16) @ Wo + bo + query ; single barrier ----------------
__global__ __launch_bounds__(256) void gemm_out_kernel(
    const u16* __restrict__ A, const float* __restrict__ W,
    const float* __restrict__ bias, const float* __restrict__ resid,
    float* __restrict__ outf)
{
    __shared__ __align__(16) u16 Ws[32][776];
    int tid  = threadIdx.x;
    int wave = tid >> 6, lane = tid & 63;
    int qm   = lane & 15;
    int quad = lane >> 4;
    int id = blockIdx.x;
    int m0 = (id & 31) * 64;
    int n0 = (id >> 5) * 32;
    int sn = tid & 31, sk = tid >> 5;

    int row = m0 + wave*16 + qm;
    const u16* Ab = A + (size_t)row*D_;

    short8 ar[8];
    #pragma unroll
    for (int t = 0; t < 8; t++) ar[t] = *(const short8*)(Ab + t*32 + quad*8);
    {
        const float* Wb = W + n0 + sn;
        #pragma unroll
        for (int k = 0; k < 96; k++)
            Ws[sn][sk + k*8] = f2bf(Wb[(size_t)(sk + k*8)*D_]);
    }
    __syncthreads();

    floatx4 acc[2];
    acc[0] = (floatx4){0,0,0,0};
    acc[1] = (floatx4){0,0,0,0};
    #pragma unroll
    for (int kc = 0; kc < 24; kc++) {
        short8 a = ar[kc & 7];
        if (kc < 16) ar[kc & 7] = *(const short8*)(Ab + (kc+8)*32 + quad*8);
        #pragma unroll
        for (int bt = 0; bt < 2; bt++) {
            short8 b = *(const short8*)&Ws[bt*16 + qm][kc*32 + quad*8];
            acc[bt] = __builtin_amdgcn_mfma_f32_16x16x32_bf16(a, b, acc[bt], 0,0,0);
        }
    }

    #pragma unroll
    for (int bt = 0; bt < 2; bt++) {
        int c = n0 + bt*16 + qm;
        #pragma unroll
        for (int g = 0; g < 4; g++) {
            int r2 = m0 + wave*16 + quad*4 + g;
            outf[(size_t)r2*D_ + c] = acc[bt][g] + bias[c] + resid[(size_t)r2*D_ + c];
        }
    }
}

// ---------------- Kernel C: MFMA fused rel-attention v5 (fragment-plane loads) ----------------
__global__ __launch_bounds__(256, 2) void attn_kernel(
    const u16* __restrict__ qq,
    const u16* __restrict__ kf, const u16* __restrict__ vf,
    const u16* __restrict__ Rf,
    const float* __restrict__ rwb, const float* __restrict__ rrb,
    u16* __restrict__ av)
{
    __shared__ char smem[64*1024];
    u16* SC  = (u16*)smem;            // [16][1024] content scores -> probs
    u16* PSC = (u16*)(smem + 32768);  // [16][1024] pos scores
    int tid  = threadIdx.x;
    int wave = tid >> 6, lane = tid & 63;
    int qm   = lane & 15;
    int quad = lane >> 4;
    int k8   = quad * 8;
    int blkid = blockIdx.x;
    int xcd = blkid & 7;
    int sl  = blkid >> 3;
    int it  = sl & 63;
    int seg = sl >> 6;
    int bn  = xcd + 8*seg;
    int b = bn / H_, n = bn % H_;
    int i0 = it * 16;
    size_t hbase = (size_t)bn * S_ * DH;

    // ---- Q fragments (row-major qq; only 4 loads) ----
    short8 qcf[2], qpf[2];
    #pragma unroll
    for (int s = 0; s < 2; s++) {
        const u16* qptr = qq + hbase + (size_t)(i0 + qm)*DH + s*32 + k8;
        const float* rwp = rwb + n*DH + s*32 + k8;
        const float* rrp = rrb + n*DH + s*32 + k8;
        #pragma unroll
        for (int j = 0; j < 8; j++) {
            float qv = bf2f(qptr[j]);
            qcf[s][j] = (short)f2bf(qv + rwp[j]*SCALEF);
            qpf[s][j] = (short)f2bf(qv + rrp[j]*SCALEF);
        }
    }

    // ---- Phase 1: content scores -> SC; fully-coalesced fragment loads ----
    {
        const u16* kbb = kf + ((size_t)bn*64 + wave*16)*1024 + lane*8;
        short8 rb[8][2];
        #pragma unroll
        for (int t = 0; t < 8; t++) {
            rb[t][0] = *(const short8*)(kbb + t*1024);
            rb[t][1] = *(const short8*)(kbb + t*1024 + 512);
        }
        #pragma unroll
        for (int t = 0; t < 16; t++) {
            short8 b0 = rb[t & 7][0], b1 = rb[t & 7][1];
            if (t < 8) {
                rb[t & 7][0] = *(const short8*)(kbb + (t+8)*1024);
                rb[t & 7][1] = *(const short8*)(kbb + (t+8)*1024 + 512);
            }
            floatx4 acc = {0.f,0.f,0.f,0.f};
            acc = __builtin_amdgcn_mfma_f32_16x16x32_bf16(qcf[0], b0, acc, 0,0,0);
            acc = __builtin_amdgcn_mfma_f32_16x16x32_bf16(qcf[1], b1, acc, 0,0,0);
            int j0 = (wave*16 + t) * 16;
            #pragma unroll
            for (int g = 0; g < 4; g++)
                SC[(quad*4 + g)*1024 + j0 + qm] = f2bf(acc[g]);
        }
    }

    // ---- Phase 2: pos scores -> PSC; u-tiles absolute: ut = 63 - it + m ----
    {
        const u16* rbb = Rf + (size_t)n*131072 + lane*8;
        int ut0 = 63 - it;
        short8 rb[8][2];
        #pragma unroll
        for (int t = 0; t < 8; t++) {
            int ut = ut0 + t*4 + wave;
            rb[t][0] = *(const short8*)(rbb + (size_t)ut*1024);
            rb[t][1] = *(const short8*)(rbb + (size_t)ut*1024 + 512);
        }
        #pragma unroll
        for (int t = 0; t < 16; t++) {
            short8 b0 = rb[t & 7][0], b1 = rb[t & 7][1];
            int uu = (ut0 + t*4 + wave)*16 + qm;
            if (t < 8) {
                int ut2 = ut0 + (t+8)*4 + wave;
                rb[t & 7][0] = *(const short8*)(rbb + (size_t)ut2*1024);
                rb[t & 7][1] = *(const short8*)(rbb + (size_t)ut2*1024 + 512);
            }
            floatx4 acc = {0.f,0.f,0.f,0.f};
            acc = __builtin_amdgcn_mfma_f32_16x16x32_bf16(qpf[0], b0, acc, 0,0,0);
            acc = __builtin_amdgcn_mfma_f32_16x16x32_bf16(qpf[1], b1, acc, 0,0,0);
            #pragma unroll
            for (int g = 0; g < 4; g++) {
                int row = quad*4 + g;
                int j = uu + i0 + row - 1024;
                if (j >= 0 && j < S_ && uu <= 2046)
                    PSC[row*1024 + j] = f2bf(acc[g]);
            }
        }
    }
    if (wave == 0) {   // 65th u-tile: ut = 127 - it
        int ut = 127 - it;
        const u16* rp = Rf + (size_t)n*131072 + (size_t)ut*1024 + lane*8;
        short8 b0 = *(const short8*)(rp);
        short8 b1 = *(const short8*)(rp + 512);
        int uu = ut*16 + qm;
        floatx4 acc = {0.f,0.f,0.f,0.f};
        acc = __builtin_amdgcn_mfma_f32_16x16x32_bf16(qpf[0], b0, acc, 0,0,0);
        acc = __builtin_amdgcn_mfma_f32_16x16x32_bf16(qpf[1], b1, acc, 0,0,0);
        #pragma unroll
        for (int g = 0; g < 4; g++) {
            int row = quad*4 + g;
            int j = uu + i0 + row - 1024;
            if (j >= 0 && j < S_ && uu <= 2046)
                PSC[row*1024 + j] = f2bf(acc[g]);
        }
    }
    // HF rel_shift wraparound: (i=0, j=1023) uses qp row 1, R row 0 (frag-plane gather)
    if (i0 == 0 && tid == 0) {
        float sdot = 0.f;
        const u16* q1p = qq + hbase + DH;
        for (int d = 0; d < DH; d++) {
            int p = d >> 5, dd = d & 31;
            u16 rv = Rf[(size_t)n*131072 + p*512 + ((dd>>3)*16 + 0)*8 + (dd&7)];
            sdot += (bf2f(q1p[d]) + rrb[n*DH + d]*SCALEF) * bf2f(rv);
        }
        PSC[1023] = f2bf(sdot);
    }
    __syncthreads();

    // ---- Phase 3: softmax (SC + PSC), vectorized; probs -> SC swizzled ----
    for (int rr = 0; rr < 4; rr++) {
        int r = wave*4 + rr;
        short8 c0 = *(const short8*)(SC  + r*1024 + lane*16);
        short8 c1 = *(const short8*)(SC  + r*1024 + lane*16 + 8);
        short8 p0 = *(const short8*)(PSC + r*1024 + lane*16);
        short8 p1 = *(const short8*)(PSC + r*1024 + lane*16 + 8);
        float p[16];
        float mx = -1e30f;
        #pragma unroll
        for (int q = 0; q < 8; q++) {
            p[q]   = bf2f((u16)c0[q]) + bf2f((u16)p0[q]);
            p[q+8] = bf2f((u16)c1[q]) + bf2f((u16)p1[q]);
        }
        #pragma unroll
        for (int q = 0; q < 16; q++) mx = fmaxf(mx, p[q]);
        #pragma unroll
        for (int off = 32; off; off >>= 1) mx = fmaxf(mx, __shfl_xor(mx, off));
        float ssum = 0.f;
        #pragma unroll
        for (int q = 0; q < 16; q++) { p[q] = __expf(p[q] - mx); ssum += p[q]; }
        #pragma unroll
        for (int off = 32; off; off >>= 1) ssum += __shfl_xor(ssum, off);
        float inv = 1.0f / ssum;
        int swz = r & 7;
        union { u16 h[8]; short8 v; } w0, w1;
        #pragma unroll
        for (int q = 0; q < 8; q++) {
            w0.h[q] = f2bf(p[q]*inv);
            w1.h[q] = f2bf(p[q+8]*inv);
        }
        *(short8*)(SC + r*1024 + (((2*lane)   ^ swz) << 3)) = w0.v;
        *(short8*)(SC + r*1024 + (((2*lane+1) ^ swz) << 3)) = w1.v;
    }

    // ---- Phase 4 preload (fragment-plane V, fully coalesced) ----
    const u16* vbase = vf + (size_t)bn*65536 + wave*512 + lane*8;
    short8 vb[8];
    #pragma unroll
    for (int t = 0; t < 8; t++) vb[t] = *(const short8*)(vbase + t*2048);
    __syncthreads();

    // ---- Phase 4: PV; ring prefetch + 4 accumulators ----
    floatx4 o[4];
    #pragma unroll
    for (int t = 0; t < 4; t++) o[t] = (floatx4){0.f,0.f,0.f,0.f};
    int aswz = qm & 7;
    #pragma unroll
    for (int kt = 0; kt < 32; kt++) {
        short8 bfr = vb[kt & 7];
        if (kt < 24) vb[kt & 7] = *(const short8*)(vbase + (size_t)(kt+8)*2048);
        int chunk = (kt*4 + quad) ^ aswz;
        short8 a = *(const short8*)(SC + qm*1024 + (chunk << 3));
        o[kt & 3] = __builtin_amdgcn_mfma_f32_16x16x32_bf16(a, bfr, o[kt & 3], 0,0,0);
    }
    floatx4 os = (o[0] + o[1]) + (o[2] + o[3]);
    int d0 = wave*16;
    #pragma unroll
    for (int g = 0; g < 4; g++) {
        int row = quad*4 + g;
        av[((size_t)(b*S_) + i0 + row)*D_ + n*DH + d0 + qm] = f2bf(os[g]);
    }
}

// ---------------- Kernel E: in-place LayerNorm (float4 I/O) ----------------
__global__ __launch_bounds__(256) void ln_kernel(
    const float* __restrict__ gamma, const float* __restrict__ beta,
    float* out)
{
    __shared__ float hb[8][D_];
    int tid = threadIdx.x;
    int rowg0 = blockIdx.x * 8;
    #pragma unroll
    for (int p = 0; p < 6; p++) {
        int id = p*256 + tid;
        int r = id / 192, e4 = id % 192;
        *(float4*)&hb[r][e4*4] = *(const float4*)&out[(size_t)(rowg0 + r)*D_ + e4*4];
    }
    __syncthreads();
    int wave = tid >> 6, lane = tid & 63;
    for (int rr = 0; rr < 2; rr++) {
        int r = wave*2 + rr;
        float s = 0.f;
        #pragma unroll
        for (int kq = 0; kq < 12; kq++) s += hb[r][lane + kq*64];
        #pragma unroll
        for (int off = 32; off; off >>= 1) s += __shfl_xor(s, off);
        float mu = s * (1.0f/768.0f);
        float vsum = 0.f;
        #pragma unroll
        for (int kq = 0; kq < 12; kq++) { float d = hb[r][lane + kq*64] - mu; vsum += d*d; }
        #pragma unroll
        for (int off = 32; off; off >>= 1) vsum += __shfl_xor(vsum, off);
        float rstd = rsqrtf(vsum * (1.0f/768.0f) + 1e-9f);
        #pragma unroll
        for (int kq = 0; kq < 3; kq++) {
            int c4 = lane + kq*64;
            float4 g4 = *(const float4*)&gamma[c4*4];
            float4 b4 = *(const float4*)&beta[c4*4];
            float4 h4 = *(const float4*)&hb[r][c4*4];
            float4 o4;
            o4.x = (h4.x - mu)*rstd*g4.x + b4.x;
            o4.y = (h4.y - mu)*rstd*g4.y + b4.y;
            o4.z = (h4.z - mu)*rstd*g4.z + b4.z;
            o4.w = (h4.w - mu)*rstd*g4.w + b4.w;
            *(float4*)&out[(size_t)(rowg0 + r)*D_ + c4*4] = o4;
        }
    }
}

extern "C" void kernel_launch(void* const* d_in, const int* in_sizes, int n_in,
                              void* d_out, int out_size, void* d_ws, size_t ws_size,
                              hipStream_t stream) {
    const float* query = (const float*)d_in[0];
    const float* pe    = (const float*)d_in[1];
    const float* Wq    = (const float*)d_in[2];
    const float* Wk    = (const float*)d_in[3];
    const float* bk    = (const float*)d_in[4];
    const float* Wv    = (const float*)d_in[5];
    const float* bv    = (const float*)d_in[6];
    const float* rk    = (const float*)d_in[7];
    const float* rwb   = (const float*)d_in[8];
    const float* rrb   = (const float*)d_in[9];
    const float* Wo    = (const float*)d_in[10];
    const float* bo    = (const float*)d_in[11];
    const float* gamma = (const float*)d_in[12];
    const float* beta  = (const float*)d_in[13];
    float* out = (float*)d_out;

    u16* ws = (u16*)d_ws;
    const size_t SEG = (size_t)B_*H_*S_*DH;       // 1,572,864 elems (3 MB bf16)
    u16* qq = ws;             // [bn][s][d] row-major
    u16* kf = qq + SEG;       // K fragment planes
    u16* vf = kf + SEG;       // V fragment planes
    u16* Rf = vf + SEG;       // R fragment planes (12 x 128 tiles)
    u16* av = Rf + SEG;       // [b*S+s][n*64+d] bf16 attn_vec

    pre_kernel<<<1536, 256, 0, stream>>>(query, Wq, Wk, Wv, bk, bv, qq, kf, vf, pe, rk, Rf);
    attn_kernel<<<1536, 256, 0, stream>>>(qq, kf, vf, Rf, rwb, rrb, av);
    gemm_out_kernel<<<768, 256, 0, stream>>>(av, Wo, bo, query, out);
    ln_kernel<<<256, 256, 0, stream>>>(gamma, beta, out);
}

// Round 14
// 173.986 us; speedup vs baseline: 1.2201x; 1.0215x over previous
//
#include <hip/hip_runtime.h>
#include <stdint.h>

#define B_ 2
#define S_ 1024
#define D_ 768
#define H_ 12
#define DH 64
#define G_ 4
#define DG 192
#define T_ 2047
#define SCALEF 0.125f

typedef unsigned short u16;
typedef unsigned int u32;
typedef __attribute__((ext_vector_type(8))) short short8;
typedef __attribute__((ext_vector_type(4))) float floatx4;

__device__ __forceinline__ float uas(u32 x){ union { u32 i; float f; } v; v.i = x; return v.f; }
__device__ __forceinline__ float bf2f(u16 u){ return uas(((u32)u) << 16); }
__device__ __forceinline__ u16 f2bf(float f){
    union { float f; u32 i; } v; v.f = f;
    u32 x = v.i;
    u32 r = (x + 0x7fffu + ((x >> 16) & 1u)) >> 16;  // RNE
    return (u16)r;
}
__device__ __forceinline__ short8 cvt8(float4 x, float4 y){
    union { u16 h[8]; short8 v; } u;
    u.h[0]=f2bf(x.x); u.h[1]=f2bf(x.y); u.h[2]=f2bf(x.z); u.h[3]=f2bf(x.w);
    u.h[4]=f2bf(y.x); u.h[5]=f2bf(y.y); u.h[6]=f2bf(y.z); u.h[7]=f2bf(y.w);
    return u.v;
}

// Fragment-plane layouts (all u16 units):
//  kf[bn][jt(64)]   : tile = 1024 u16 = {plane p(2)}[512]; entry (p,lane,j) = K[jt*16+(lane&15)][p*32+(lane>>4)*8+j]
//  Rf[n][ut(128)]   : same shape; = Rhead[ut*16+(lane&15)][...]  (u=2047 slots unwritten, discarded by guard)
//  vf[bn][kt(32)]   : 4 dslices x 512; (ds,lane,j) = V[kt*32+(lane>>4)*8+j][ds*16+(lane&15)]
//  avf[mt(128)][kc(24)] : 512; entry (lane,j) = av[mt*16+(lane&15)][kc*32+(lane>>4)*8+j]

// ---------------- Kernel PRE: merged proj (0..767) + rhead (768..1535) ----------------
__global__ __launch_bounds__(256) void pre_kernel(
    const float* __restrict__ query,
    const float* __restrict__ Wq, const float* __restrict__ Wk, const float* __restrict__ Wv,
    const float* __restrict__ bk, const float* __restrict__ bv,
    u16* __restrict__ qq, u16* __restrict__ kf, u16* __restrict__ vf,
    const float* __restrict__ pe, const float* __restrict__ rk,
    u16* __restrict__ Rf)
{
    __shared__ __align__(16) char sm[49664];
    int tid  = threadIdx.x;
    int wave = tid >> 6, lane = tid & 63;
    int qm   = lane & 15;
    int quad = lane >> 4;
    int id = blockIdx.x;
    int sn = tid & 31, sk = tid >> 5;

    if (id < 768) {
        // ========== proj: 64 rows x (group g, 32 cols); K=192, ONE barrier ==========
        typedef u16 (*W3T)[32][200];
        W3T Ws = (W3T)sm;
        int m0 = (id & 31) * 64;
        int gy = id >> 5;
        int g  = gy / 6;
        int n0 = (gy % 6) * 32;
        const float* Wm[3] = { Wq, Wk, Wv };

        int row = m0 + wave*16 + qm;
        const float* Ab = query + (size_t)row*D_ + g*DG;
        float4 fx[6], fy[6];
        #pragma unroll
        for (int kc = 0; kc < 6; kc++) {
            fx[kc] = *(const float4*)(Ab + kc*32 + quad*8);
            fy[kc] = *(const float4*)(Ab + kc*32 + quad*8 + 4);
        }
        #pragma unroll
        for (int md = 0; md < 3; md++) {
            const float* W = Wm[md] + (size_t)g*DG*DG + n0 + sn;
            #pragma unroll
            for (int k = 0; k < 24; k++)
                Ws[md][sn][sk + k*8] = f2bf(W[(size_t)(sk + k*8)*DG]);
        }
        __syncthreads();

        short8 af[6];
        #pragma unroll
        for (int kc = 0; kc < 6; kc++) af[kc] = cvt8(fx[kc], fy[kc]);

        floatx4 acc[3][2];
        #pragma unroll
        for (int md = 0; md < 3; md++) { acc[md][0] = (floatx4){0,0,0,0}; acc[md][1] = (floatx4){0,0,0,0}; }
        #pragma unroll
        for (int kc = 0; kc < 6; kc++) {
            short8 a = af[kc];
            #pragma unroll
            for (int md = 0; md < 3; md++) {
                #pragma unroll
                for (int bt = 0; bt < 2; bt++) {
                    short8 b = *(const short8*)&Ws[md][bt*16 + qm][kc*32 + quad*8];
                    acc[md][bt] = __builtin_amdgcn_mfma_f32_16x16x32_bf16(a, b, acc[md][bt], 0,0,0);
                }
            }
        }

        int rowbase = m0 + wave*16 + quad*4;
        int b  = rowbase >> 10;
        int s0 = rowbase & 1023;
        #pragma unroll
        for (int bt = 0; bt < 2; bt++) {
            int c = g*DG + n0 + bt*16 + qm;
            int n = c >> 6, d = c & 63;
            int bn = b*H_ + n;
            int p  = d >> 5, dd = d & 31;
            int qv = (dd >> 3) * 16, jj = dd & 7;
            int ds = d >> 4, qmv = d & 15;
            float bkv = bk[c], bvv = bv[c];
            #pragma unroll
            for (int gg = 0; gg < 4; gg++) {
                int s = s0 + gg;
                qq[((size_t)bn*S_ + s)*DH + d] = f2bf(acc[0][bt][gg]*SCALEF);
                kf[((size_t)bn*64 + (s>>4))*1024 + p*512 + (qv + (s&15))*8 + jj]
                    = f2bf(acc[1][bt][gg] + bkv);
                vf[(((size_t)bn*32 + (s>>5))*4 + ds)*512 + (((s>>3)&3)*16 + qmv)*8 + (s&7)]
                    = f2bf(acc[2][bt][gg] + bvv);
            }
        }
    } else {
        // ========== rhead: pe[2047,768] @ rk -> Rf ; 64 rows x 32 cols, K=768, ONE barrier ==========
        typedef u16 (*WsT)[776];
        WsT Ws = (WsT)sm;
        int id2 = id - 768;
        int m0 = (id2 & 31) * 64;
        int n0 = (id2 >> 5) * 32;

        int row = m0 + wave*16 + qm;
        int rowc = (row <= 2046) ? row : 2046;
        const float* Ab = pe + (size_t)rowc*D_;

        float4 fr[4][2];
        #pragma unroll
        for (int t = 0; t < 4; t++) {
            fr[t][0] = *(const float4*)(Ab + t*32 + quad*8);
            fr[t][1] = *(const float4*)(Ab + t*32 + quad*8 + 4);
        }
        {
            const float* W = rk + n0 + sn;
            #pragma unroll
            for (int k = 0; k < 96; k++)
                Ws[sn][sk + k*8] = f2bf(W[(size_t)(sk + k*8)*D_]);
        }
        __syncthreads();

        floatx4 acc[2];
        acc[0] = (floatx4){0,0,0,0};
        acc[1] = (floatx4){0,0,0,0};
        #pragma unroll
        for (int kc = 0; kc < 24; kc++) {
            float4 x = fr[kc & 3][0], y = fr[kc & 3][1];
            if (kc < 20) {
                fr[kc & 3][0] = *(const float4*)(Ab + (kc+4)*32 + quad*8);
                fr[kc & 3][1] = *(const float4*)(Ab + (kc+4)*32 + quad*8 + 4);
            }
            short8 a = cvt8(x, y);
            #pragma unroll
            for (int bt = 0; bt < 2; bt++) {
                short8 b = *(const short8*)&Ws[bt*16 + qm][kc*32 + quad*8];
                acc[bt] = __builtin_amdgcn_mfma_f32_16x16x32_bf16(a, b, acc[bt], 0,0,0);
            }
        }

        #pragma unroll
        for (int bt = 0; bt < 2; bt++) {
            int c = n0 + bt*16 + qm;
            int n = c >> 6, d = c & 63;
            int p = d >> 5, dd = d & 31;
            int qv = (dd >> 3) * 16, jj = dd & 7;
            #pragma unroll
            for (int g = 0; g < 4; g++) {
                int t = m0 + wave*16 + quad*4 + g;
                if (t < T_)
                    Rf[((size_t)n*128 + (t>>4))*1024 + p*512 + (qv + (t&15))*8 + jj]
                        = f2bf(acc[bt][g]);
            }
        }
    }
}

// ---------------- out GEMM: h = avf(bf16, frag-plane) @ Wo + bo + query ----------------
__global__ __launch_bounds__(256) void gemm_out_kernel(
    const u16* __restrict__ A, const float* __restrict__ W,
    const float* __restrict__ bias, const float* __restrict__ resid,
    float* __restrict__ outf)
{
    __shared__ __align__(16) u16 Ws[32][776];
    int tid  = threadIdx.x;
    int wave = tid >> 6, lane = tid & 63;
    int qm   = lane & 15;
    int quad = lane >> 4;
    int id = blockIdx.x;
    int m0 = (id & 31) * 64;
    int n0 = (id >> 5) * 32;
    int sn = tid & 31, sk = tid >> 5;

    // A from fragment-plane: mt = m0/16 + wave; fully coalesced lane*8 loads
    const u16* Ab = A + ((size_t)((id & 31)*4 + wave))*12288 + lane*8;

    short8 ar[8];
    #pragma unroll
    for (int t = 0; t < 8; t++) ar[t] = *(const short8*)(Ab + t*512);
    {
        const float* Wb = W + n0 + sn;
        #pragma unroll
        for (int k = 0; k < 96; k++)
            Ws[sn][sk + k*8] = f2bf(Wb[(size_t)(sk + k*8)*D_]);
    }
    __syncthreads();

    floatx4 acc[2];
    acc[0] = (floatx4){0,0,0,0};
    acc[1] = (floatx4){0,0,0,0};
    #pragma unroll
    for (int kc = 0; kc < 24; kc++) {
        short8 a = ar[kc & 7];
        if (kc < 16) ar[kc & 7] = *(const short8*)(Ab + (size_t)(kc+8)*512);
        #pragma unroll
        for (int bt = 0; bt < 2; bt++) {
            short8 b = *(const short8*)&Ws[bt*16 + qm][kc*32 + quad*8];
            acc[bt] = __builtin_amdgcn_mfma_f32_16x16x32_bf16(a, b, acc[bt], 0,0,0);
        }
    }

    #pragma unroll
    for (int bt = 0; bt < 2; bt++) {
        int c = n0 + bt*16 + qm;
        #pragma unroll
        for (int g = 0; g < 4; g++) {
            int r2 = m0 + wave*16 + quad*4 + g;
            outf[(size_t)r2*D_ + c] = acc[bt][g] + bias[c] + resid[(size_t)r2*D_ + c];
        }
    }
}

// ---------------- Kernel C: MFMA fused rel-attention v5 (fragment-plane I/O) ----------------
__global__ __launch_bounds__(256, 2) void attn_kernel(
    const u16* __restrict__ qq,
    const u16* __restrict__ kf, const u16* __restrict__ vf,
    const u16* __restrict__ Rf,
    const float* __restrict__ rwb, const float* __restrict__ rrb,
    u16* __restrict__ avf)
{
    __shared__ char smem[64*1024];
    u16* SC  = (u16*)smem;            // [16][1024] content scores -> probs
    u16* PSC = (u16*)(smem + 32768);  // [16][1024] pos scores
    int tid  = threadIdx.x;
    int wave = tid >> 6, lane = tid & 63;
    int qm   = lane & 15;
    int quad = lane >> 4;
    int k8   = quad * 8;
    int blkid = blockIdx.x;
    int xcd = blkid & 7;
    int sl  = blkid >> 3;
    int it  = sl & 63;
    int seg = sl >> 6;
    int bn  = xcd + 8*seg;
    int b = bn / H_, n = bn % H_;
    int i0 = it * 16;
    size_t hbase = (size_t)bn * S_ * DH;

    // ---- Q fragments ----
    short8 qcf[2], qpf[2];
    #pragma unroll
    for (int s = 0; s < 2; s++) {
        const u16* qptr = qq + hbase + (size_t)(i0 + qm)*DH + s*32 + k8;
        const float* rwp = rwb + n*DH + s*32 + k8;
        const float* rrp = rrb + n*DH + s*32 + k8;
        #pragma unroll
        for (int j = 0; j < 8; j++) {
            float qv = bf2f(qptr[j]);
            qcf[s][j] = (short)f2bf(qv + rwp[j]*SCALEF);
            qpf[s][j] = (short)f2bf(qv + rrp[j]*SCALEF);
        }
    }

    // ---- Phase 1: content scores -> SC; coalesced fragment loads ----
    {
        const u16* kbb = kf + ((size_t)bn*64 + wave*16)*1024 + lane*8;
        short8 rb[8][2];
        #pragma unroll
        for (int t = 0; t < 8; t++) {
            rb[t][0] = *(const short8*)(kbb + t*1024);
            rb[t][1] = *(const short8*)(kbb + t*1024 + 512);
        }
        #pragma unroll
        for (int t = 0; t < 16; t++) {
            short8 b0 = rb[t & 7][0], b1 = rb[t & 7][1];
            if (t < 8) {
                rb[t & 7][0] = *(const short8*)(kbb + (t+8)*1024);
                rb[t & 7][1] = *(const short8*)(kbb + (t+8)*1024 + 512);
            }
            floatx4 acc = {0.f,0.f,0.f,0.f};
            acc = __builtin_amdgcn_mfma_f32_16x16x32_bf16(qcf[0], b0, acc, 0,0,0);
            acc = __builtin_amdgcn_mfma_f32_16x16x32_bf16(qcf[1], b1, acc, 0,0,0);
            int j0 = (wave*16 + t) * 16;
            #pragma unroll
            for (int g = 0; g < 4; g++)
                SC[(quad*4 + g)*1024 + j0 + qm] = f2bf(acc[g]);
        }
    }

    // ---- Phase 2: pos scores -> PSC; u-tiles absolute: ut = 63 - it + m ----
    {
        const u16* rbb = Rf + (size_t)n*131072 + lane*8;
        int ut0 = 63 - it;
        short8 rb[8][2];
        #pragma unroll
        for (int t = 0; t < 8; t++) {
            int ut = ut0 + t*4 + wave;
            rb[t][0] = *(const short8*)(rbb + (size_t)ut*1024);
            rb[t][1] = *(const short8*)(rbb + (size_t)ut*1024 + 512);
        }
        #pragma unroll
        for (int t = 0; t < 16; t++) {
            short8 b0 = rb[t & 7][0], b1 = rb[t & 7][1];
            int uu = (ut0 + t*4 + wave)*16 + qm;
            if (t < 8) {
                int ut2 = ut0 + (t+8)*4 + wave;
                rb[t & 7][0] = *(const short8*)(rbb + (size_t)ut2*1024);
                rb[t & 7][1] = *(const short8*)(rbb + (size_t)ut2*1024 + 512);
            }
            floatx4 acc = {0.f,0.f,0.f,0.f};
            acc = __builtin_amdgcn_mfma_f32_16x16x32_bf16(qpf[0], b0, acc, 0,0,0);
            acc = __builtin_amdgcn_mfma_f32_16x16x32_bf16(qpf[1], b1, acc, 0,0,0);
            #pragma unroll
            for (int g = 0; g < 4; g++) {
                int row = quad*4 + g;
                int j = uu + i0 + row - 1024;
                if (j >= 0 && j < S_ && uu <= 2046)
                    PSC[row*1024 + j] = f2bf(acc[g]);
            }
        }
    }
    if (wave == 0) {   // 65th u-tile: ut = 127 - it
        int ut = 127 - it;
        const u16* rp = Rf + (size_t)n*131072 + (size_t)ut*1024 + lane*8;
        short8 b0 = *(const short8*)(rp);
        short8 b1 = *(const short8*)(rp + 512);
        int uu = ut*16 + qm;
        floatx4 acc = {0.f,0.f,0.f,0.f};
        acc = __builtin_amdgcn_mfma_f32_16x16x32_bf16(qpf[0], b0, acc, 0,0,0);
        acc = __builtin_amdgcn_mfma_f32_16x16x32_bf16(qpf[1], b1, acc, 0,0,0);
        #pragma unroll
        for (int g = 0; g < 4; g++) {
            int row = quad*4 + g;
            int j = uu + i0 + row - 1024;
            if (j >= 0 && j < S_ && uu <= 2046)
                PSC[row*1024 + j] = f2bf(acc[g]);
        }
    }
    // HF rel_shift wraparound: (i=0, j=1023) uses qp row 1, R row 0 (frag-plane gather)
    if (i0 == 0 && tid == 0) {
        float sdot = 0.f;
        const u16* q1p = qq + hbase + DH;
        for (int d = 0; d < DH; d++) {
            int p = d >> 5, dd = d & 31;
            u16 rv = Rf[(size_t)n*131072 + p*512 + ((dd>>3)*16 + 0)*8 + (dd&7)];
            sdot += (bf2f(q1p[d]) + rrb[n*DH + d]*SCALEF) * bf2f(rv);
        }
        PSC[1023] = f2bf(sdot);
    }
    __syncthreads();

    // ---- Phase 3: softmax (SC + PSC), vectorized; probs -> SC swizzled ----
    for (int rr = 0; rr < 4; rr++) {
        int r = wave*4 + rr;
        short8 c0 = *(const short8*)(SC  + r*1024 + lane*16);
        short8 c1 = *(const short8*)(SC  + r*1024 + lane*16 + 8);
        short8 p0 = *(const short8*)(PSC + r*1024 + lane*16);
        short8 p1 = *(const short8*)(PSC + r*1024 + lane*16 + 8);
        float p[16];
        float mx = -1e30f;
        #pragma unroll
        for (int q = 0; q < 8; q++) {
            p[q]   = bf2f((u16)c0[q]) + bf2f((u16)p0[q]);
            p[q+8] = bf2f((u16)c1[q]) + bf2f((u16)p1[q]);
        }
        #pragma unroll
        for (int q = 0; q < 16; q++) mx = fmaxf(mx, p[q]);
        #pragma unroll
        for (int off = 32; off; off >>= 1) mx = fmaxf(mx, __shfl_xor(mx, off));
        float ssum = 0.f;
        #pragma unroll
        for (int q = 0; q < 16; q++) { p[q] = __expf(p[q] - mx); ssum += p[q]; }
        #pragma unroll
        for (int off = 32; off; off >>= 1) ssum += __shfl_xor(ssum, off);
        float inv = 1.0f / ssum;
        int swz = r & 7;
        union { u16 h[8]; short8 v; } w0, w1;
        #pragma unroll
        for (int q = 0; q < 8; q++) {
            w0.h[q] = f2bf(p[q]*inv);
            w1.h[q] = f2bf(p[q+8]*inv);
        }
        *(short8*)(SC + r*1024 + (((2*lane)   ^ swz) << 3)) = w0.v;
        *(short8*)(SC + r*1024 + (((2*lane+1) ^ swz) << 3)) = w1.v;
    }

    // ---- Phase 4 preload (fragment-plane V, coalesced) ----
    const u16* vbase = vf + (size_t)bn*65536 + wave*512 + lane*8;
    short8 vb[8];
    #pragma unroll
    for (int t = 0; t < 8; t++) vb[t] = *(const short8*)(vbase + t*2048);
    __syncthreads();

    // ---- Phase 4: PV; ring prefetch + 4 accumulators ----
    floatx4 o[4];
    #pragma unroll
    for (int t = 0; t < 4; t++) o[t] = (floatx4){0.f,0.f,0.f,0.f};
    int aswz = qm & 7;
    #pragma unroll
    for (int kt = 0; kt < 32; kt++) {
        short8 bfr = vb[kt & 7];
        if (kt < 24) vb[kt & 7] = *(const short8*)(vbase + (size_t)(kt+8)*2048);
        int chunk = (kt*4 + quad) ^ aswz;
        short8 a = *(const short8*)(SC + qm*1024 + (chunk << 3));
        o[kt & 3] = __builtin_amdgcn_mfma_f32_16x16x32_bf16(a, bfr, o[kt & 3], 0,0,0);
    }
    floatx4 os = (o[0] + o[1]) + (o[2] + o[3]);
    // ---- write attn_vec in fragment-plane layout for gemm_out ----
    // avf[mt = b*64+it][kc = n*2 + (wave>>1)], entry = (ks8*16 + m_sub)*8 + j
    // ks8 = (wave&1)*2 + (qm>>3); m_sub = quad*4+g; j = qm&7
    {
        size_t abase = ((size_t)(b*64 + it))*12288 + (size_t)(n*2 + (wave>>1))*512
                     + (size_t)(((wave&1)*2 + (qm>>3))*16 + quad*4)*8 + (qm&7);
        #pragma unroll
        for (int g = 0; g < 4; g++)
            avf[abase + g*8] = f2bf(os[g]);
    }
}

// ---------------- Kernel E: in-place LayerNorm (float4 I/O) ----------------
__global__ __launch_bounds__(256) void ln_kernel(
    const float* __restrict__ gamma, const float* __restrict__ beta,
    float* out)
{
    __shared__ float hb[8][D_];
    int tid = threadIdx.x;
    int rowg0 = blockIdx.x * 8;
    #pragma unroll
    for (int p = 0; p < 6; p++) {
        int id = p*256 + tid;
        int r = id / 192, e4 = id % 192;
        *(float4*)&hb[r][e4*4] = *(const float4*)&out[(size_t)(rowg0 + r)*D_ + e4*4];
    }
    __syncthreads();
    int wave = tid >> 6, lane = tid & 63;
    for (int rr = 0; rr < 2; rr++) {
        int r = wave*2 + rr;
        float s = 0.f;
        #pragma unroll
        for (int kq = 0; kq < 12; kq++) s += hb[r][lane + kq*64];
        #pragma unroll
        for (int off = 32; off; off >>= 1) s += __shfl_xor(s, off);
        float mu = s * (1.0f/768.0f);
        float vsum = 0.f;
        #pragma unroll
        for (int kq = 0; kq < 12; kq++) { float d = hb[r][lane + kq*64] - mu; vsum += d*d; }
        #pragma unroll
        for (int off = 32; off; off >>= 1) vsum += __shfl_xor(vsum, off);
        float rstd = rsqrtf(vsum * (1.0f/768.0f) + 1e-9f);
        #pragma unroll
        for (int kq = 0; kq < 3; kq++) {
            int c4 = lane + kq*64;
            float4 g4 = *(const float4*)&gamma[c4*4];
            float4 b4 = *(const float4*)&beta[c4*4];
            float4 h4 = *(const float4*)&hb[r][c4*4];
            float4 o4;
            o4.x = (h4.x - mu)*rstd*g4.x + b4.x;
            o4.y = (h4.y - mu)*rstd*g4.y + b4.y;
            o4.z = (h4.z - mu)*rstd*g4.z + b4.z;
            o4.w = (h4.w - mu)*rstd*g4.w + b4.w;
            *(float4*)&out[(size_t)(rowg0 + r)*D_ + c4*4] = o4;
        }
    }
}

extern "C" void kernel_launch(void* const* d_in, const int* in_sizes, int n_in,
                              void* d_out, int out_size, void* d_ws, size_t ws_size,
                              hipStream_t stream) {
    const float* query = (const float*)d_in[0];
    const float* pe    = (const float*)d_in[1];
    const float* Wq    = (const float*)d_in[2];
    const float* Wk    = (const float*)d_in[3];
    const float* bk    = (const float*)d_in[4];
    const float* Wv    = (const float*)d_in[5];
    const float* bv    = (const float*)d_in[6];
    const float* rk    = (const float*)d_in[7];
    const float* rwb   = (const float*)d_in[8];
    const float* rrb   = (const float*)d_in[9];
    const float* Wo    = (const float*)d_in[10];
    const float* bo    = (const float*)d_in[11];
    const float* gamma = (const float*)d_in[12];
    const float* beta  = (const float*)d_in[13];
    float* out = (float*)d_out;

    u16* ws = (u16*)d_ws;
    const size_t SEG = (size_t)B_*H_*S_*DH;       // 1,572,864 elems (3 MB bf16)
    u16* qq  = ws;            // [bn][s][d] row-major
    u16* kf  = qq + SEG;      // K fragment planes
    u16* vf  = kf + SEG;      // V fragment planes
    u16* Rf  = vf + SEG;      // R fragment planes (12 x 128 tiles)
    u16* avf = Rf + SEG;      // attn_vec fragment planes [128 mt][24 kc][512]

    pre_kernel<<<1536, 256, 0, stream>>>(query, Wq, Wk, Wv, bk, bv, qq, kf, vf, pe, rk, Rf);
    attn_kernel<<<1536, 256, 0, stream>>>(qq, kf, vf, Rf, rwb, rrb, avf);
    gemm_out_kernel<<<768, 256, 0, stream>>>(avf, Wo, bo, query, out);
    ln_kernel<<<256, 256, 0, stream>>>(gamma, beta, out);
}